// Round 12
// baseline (324.409 us; speedup 1.0000x reference)
//
#include <hip/hip_runtime.h>
#include <stdint.h>

#define NL   12
#define PTOT 32936
#define LMB  32778
#define NCH  515           // ceil(PTOT/64) words of positivity bits
#define NCHP 520           // padded LDS words
#define NGRP 129           // ceil(NCH/4) 256-elem groups (64 float4 / group)
#define BMW  (NGRP * 4)    // 516 contiguous-bit words
#define TPAD (NGRP * 256)  // 33024 padded table elems
#define NSEG 445           // 12 layers * 37 segments + 1 LM segment
#define TPB  512           // threads per block (8 waves)
#define NWV  (TPB / 64)
#define NITER ((NGRP + NWV - 1) / NWV)   // 17 groups per wave (statically unrolled)

typedef float vf4 __attribute__((ext_vector_type(4)));

__device__ __constant__ int c_base[NL] = {0,86,653,1701,3230,5240,7731,10703,14156,18090,22505,27401};

__device__ __forceinline__ uint64_t ext(const uint64_t* P, uint32_t off) {
  uint32_t w = off >> 6, s = off & 63;
  uint64_t lo = P[w], hi = P[w + 1];
  return s ? ((lo >> s) | (hi << (64 - s))) : lo;
}

__device__ __forceinline__ uint64_t rbit(uint64_t r0, uint64_t r1, uint64_t r2, uint32_t idx) {
  uint64_t w = idx < 64 ? r0 : (idx < 128 ? r1 : r2);
  return (w >> (idx & 63)) & 1ull;
}

// register-resident ext over the 158-bit live vector (bits >=192 implied 0)
__device__ __forceinline__ uint64_t rext(uint64_t a0, uint64_t a1, uint64_t a2, uint32_t off) {
  uint32_t w = off >> 6, s = off & 63;
  uint64_t lo = (w == 0) ? a0 : ((w == 1) ? a1 : ((w == 2) ? a2 : 0ull));
  uint64_t hi = (w == 0) ? a1 : ((w == 1) ? a2 : 0ull);
  return s ? ((lo >> s) | (hi << (64 - s))) : lo;
}

__device__ __forceinline__ void orAt(uint64_t& r0, uint64_t& r1, uint64_t& r2,
                                     uint64_t val, uint32_t pos) {
  uint32_t w = pos >> 6, s = pos & 63;
  uint64_t lo = val << s;
  uint64_t hi = s ? (val >> (64 - s)) : 0ull;
  if (w == 0) { r0 |= lo; r1 |= hi; }
  else if (w == 1) { r1 |= lo; r2 |= hi; }
  else { r2 |= lo; }
}

__device__ __forceinline__ void maskLen(uint32_t len, uint64_t& m0, uint64_t& m1, uint64_t& m2) {
  m0 = (len >= 64) ? ~0ull : ((1ull << len) - 1ull);
  m1 = (len <= 64) ? 0ull : ((len >= 128) ? ~0ull : ((1ull << (len - 64)) - 1ull));
  m2 = (len <= 128) ? 0ull : ((1ull << (len - 128)) - 1ull);
}

__device__ __forceinline__ uint32_t ext12(uint64_t O0, uint64_t O1, uint64_t O2, uint32_t pos) {
  uint32_t w = pos >> 6, s = pos & 63;
  uint64_t lo = (w == 0) ? O0 : ((w == 1) ? O1 : O2);
  uint64_t hi = (w == 0) ? O1 : ((w == 1) ? O2 : 0ull);
  uint64_t v = s ? ((lo >> s) | (hi << (64 - s))) : lo;
  return (uint32_t)v & 0xFFFu;
}

// spread 16 bits to every 4th bit of a 64-bit word
__device__ __forceinline__ uint64_t spread4(uint64_t x) {
  x = (x | (x << 24)) & 0x000000FF000000FFull;
  x = (x | (x << 12)) & 0x000F000F000F000Full;
  x = (x | (x << 6))  & 0x0303030303030303ull;
  x = (x | (x << 3))  & 0x1111111111111111ull;
  return x;
}

// Phase C: forward reachability R then backward liveness O (O ⊆ R); writes
// live = R & O to sLv. Must be executed by all 64 lanes of wave 0.
__device__ __forceinline__ void graph_live(const uint64_t* sPos, uint64_t* sLv, int lane) {
  uint64_t R0 = 3ull, R1 = 0ull, R2 = 0ull;
  const int g = lane;
#pragma unroll
  for (int L = 0; L < NL; ++L) {
    const int Vq = 2 + 13 * L;
    const int b  = c_base[L];
    bool pred = false;
    if (g < 36) {
      uint32_t off = (uint32_t)(b + g * Vq);
      uint64_t e0 = ext(sPos, off), e1 = ext(sPos, off + 64), e2 = ext(sPos, off + 128);
      pred = ((e0 & R0) | (e1 & R1) | (e2 & R2)) != 0ull;
    }
    uint64_t bal = __ballot(pred);
    uint64_t ar  = bal & (bal >> 12) & (bal >> 24) & 0xFFFull;
    orAt(R0, R1, R2, ar, (uint32_t)Vq);
    const int Vm = Vq + 12;
    uint32_t offm = (uint32_t)(b + 36 * Vq);
    uint64_t e0 = ext(sPos, offm), e1 = ext(sPos, offm + 64), e2 = ext(sPos, offm + 128);
    uint64_t mr = (((e0 & R0) | (e1 & R1) | (e2 & R2)) != 0ull) ? 1ull : 0ull;
    orAt(R0, R1, R2, mr, (uint32_t)Vm);
  }
  uint64_t O0 = ext(sPos, LMB)       & R0;
  uint64_t O1 = ext(sPos, LMB + 64)  & R1;
  uint64_t O2 = ext(sPos, LMB + 128) & ((1ull << 30) - 1ull) & R2;
  const int hg = g % 12;
#pragma unroll
  for (int L = NL - 1; L >= 0; --L) {
    const int Vq = 2 + 13 * L, Vm = Vq + 12;
    const int b  = c_base[L];
    if (rbit(O0, O1, O2, (uint32_t)Vm)) {
      uint64_t m0, m1, m2; maskLen((uint32_t)Vm, m0, m1, m2);
      uint32_t offm = (uint32_t)(b + 36 * Vq);
      O0 |= ext(sPos, offm)       & R0 & m0;
      O1 |= ext(sPos, offm + 64)  & R1 & m1;
      O2 |= ext(sPos, offm + 128) & R2 & m2;
    }
    uint32_t h12 = ext12(O0, O1, O2, (uint32_t)Vq);
    uint64_t q0, q1, q2; maskLen((uint32_t)Vq, q0, q1, q2);
    uint64_t c0 = 0ull, c1 = 0ull, c2 = 0ull;
    if (g < 36 && ((h12 >> hg) & 1u)) {
      uint32_t off = (uint32_t)(b + g * Vq);
      c0 = ext(sPos, off)       & R0 & q0;
      c1 = ext(sPos, off + 64)  & R1 & q1;
      c2 = ext(sPos, off + 128) & R2 & q2;
    }
#pragma unroll
    for (int d = 32; d; d >>= 1) {
      c0 |= __shfl_xor((unsigned long long)c0, d);
      c1 |= __shfl_xor((unsigned long long)c1, d);
      c2 |= __shfl_xor((unsigned long long)c2, d);
    }
    O0 |= c0; O1 |= c1; O2 |= c2;
  }
  if (lane == 0) {
    sLv[0] = R0 & O0; sLv[1] = R1 & O1; sLv[2] = R2 & O2; sLv[3] = 0ull;
  }
}

// Phase D: per-segment shifted-window keep build (all threads; sKeep pre-zeroed)
__device__ __forceinline__ void build_keep(uint64_t* sKeep, const uint64_t* sLv, int tid) {
  const uint64_t l0 = sLv[0], l1 = sLv[1], l2 = sLv[2];
  for (int s = tid; s < NSEG; s += TPB) {
    uint32_t p0, len;
    bool olive;
    if (s == NSEG - 1) {               // LM tail: keep[i] = live[i]
      p0 = LMB; len = 158; olive = true;
    } else {
      int L = s / 37, j = s - L * 37;
      int Vq = 2 + 13 * L, b = c_base[L];
      if (j < 36) { p0 = (uint32_t)(b + j * Vq); len = (uint32_t)Vq;
                    olive = rbit(l0, l1, l2, (uint32_t)(Vq + (j % 12))) != 0ull; }
      else        { p0 = (uint32_t)(b + 36 * Vq); len = (uint32_t)(Vq + 12);
                    olive = rbit(l0, l1, l2, (uint32_t)(Vq + 12)) != 0ull; }
    }
    if (!olive) continue;
    uint32_t w0 = p0 >> 6, s0 = p0 & 63;
    uint64_t first = l0;
    if (len < 64) first &= (1ull << len) - 1ull;
    atomicOr((unsigned long long*)&sKeep[w0], (unsigned long long)(first << s0));
    uint32_t done = 64 - s0;
    uint32_t w = w0 + 1;
    while (done < len) {
      uint64_t v = rext(l0, l1, l2, done);
      uint32_t rem = len - done;
      if (rem < 64) v &= (1ull << rem) - 1ull;
      atomicOr((unsigned long long*)&sKeep[w], (unsigned long long)v);
      done += 64; ++w;
    }
  }
}

// Per-param (prob', window) SoA tables.
__global__ void init_tables(const float* __restrict__ sp, float* __restrict__ pr,
                            float* __restrict__ wd) {
  int p = blockIdx.x * blockDim.x + threadIdx.x;
  if (p >= TPAD) return;
  if (p < PTOT) {
    float x = sp[p];
    float s = 1.0f / (1.0f + expf(-x));                 // sigmoid, fp32
    float w = __fmul_rn(s, __fsub_rn(1.0f, s));         // window = p*(1-p)
    float pv = __fadd_rn(__fmul_rn(w, s), __fmul_rn(__fsub_rn(1.0f, w), s));
    pr[p] = pv; wd[p] = w;
  } else {
    pr[p] = 0.0f; wd[p] = 1.0f;
  }
}

// ---- Fused kernel: TWO rows per 512-thread block, software-pipelined --------
// Grid = bz/2 = 512 blocks = exactly 2 blocks/CU co-resident (no block-round
// tail). Schedule per block:
//   A(0)            stream row0: u -> clip(m) in mv regs, ballots -> sPos
//   [issue row1 u/pw prefetch]  <- HBM latency drains under C(0)
//   C(0)  wave 0    graph -> sLv
//   D(0)  all       sLv -> sKeep
//   FA    all       store row0 (keep-select from mv) ∥ recompute mv for row1,
//                   row1 ballots -> sPos  (same mv regs serve both rows)
//   C(1)  wave 0 ∥ waves 1-7 zero sKeep   (idle time -> D(1) setup)
//   D(1)  all
//   F(1)  all       store row1
__global__ __launch_bounds__(TPB, 4) void fused_kernel(const float* __restrict__ unif,
                                                       const vf4* __restrict__ pr4,
                                                       const vf4* __restrict__ wd4,
                                                       float* __restrict__ out) {
  __shared__ uint64_t sPos[NCHP];
  __shared__ uint64_t sKeep[NCHP];
  __shared__ uint64_t sLv[4];

  const int tid  = threadIdx.x;
  const int lane = tid & 63;
  const int wv   = tid >> 6;
  const int row0 = blockIdx.x * 2;
  const vf4* up0 = (const vf4*)(unif + (size_t)row0 * PTOT);
  const vf4* up1 = (const vf4*)(unif + (size_t)(row0 + 1) * PTOT);
  vf4*       op0 = (vf4*)(out + (size_t)row0 * PTOT);
  vf4*       op1 = (vf4*)(out + (size_t)(row0 + 1) * PTOT);

  vf4 mv[NITER];                     // registered CLIPPED m values (one row at a time)
  vf4 ub[4], pb[2], wb[2];           // circular prefetch buffers (static idx)

#define LDU(PTR, K) do { int G_ = wv + (K) * NWV; if (G_ < NGRP) {             \
    int e4_ = G_ * 64 + lane;                                                  \
    ub[(K) % 4] = (e4_ < (PTOT / 4)) ? (PTR)[e4_] : (vf4){0.f,0.f,0.f,0.f}; } } while (0)
#define LDPW(K) do { int G_ = wv + (K) * NWV; if (G_ < NGRP) {                 \
    int e4_ = G_ * 64 + lane;                                                  \
    pb[(K) % 2] = pr4[e4_]; wb[(K) % 2] = wd4[e4_]; } } while (0)

  // ---- prologue: first loads for row0; zero LDS while they fly ------------
  LDU(up0, 0); LDU(up0, 1); LDU(up0, 2); LDU(up0, 3); LDPW(0); LDPW(1);
  for (int w = tid; w < NCHP; w += TPB) sKeep[w] = 0ull;
  for (int w = BMW + tid; w < NCHP; w += TPB) sPos[w] = 0ull;

  // ---- A(0): stream row0 + clip + ballot + inline deinterleave ------------
#pragma unroll
  for (int k = 0; k < NITER; ++k) {
    const int G = wv + k * NWV;                 // wave-uniform
    if (G < NGRP) {
      vf4 u = ub[k % 4], p = pb[k % 2], w = wb[k % 2];
      int e4 = G * 64 + lane;
      bool inb = e4 < (PTOT / 4);
      float m0 = __fadd_rn(__fdiv_rn(__fsub_rn(p.x, u.x), w.x), 0.5f);
      float m1 = __fadd_rn(__fdiv_rn(__fsub_rn(p.y, u.y), w.y), 0.5f);
      float m2 = __fadd_rn(__fdiv_rn(__fsub_rn(p.z, u.z), w.z), 0.5f);
      float m3 = __fadd_rn(__fdiv_rn(__fsub_rn(p.w, u.w), w.w), 0.5f);
      mv[k] = (vf4){fminf(fmaxf(m0, 0.0f), 1.0f), fminf(fmaxf(m1, 0.0f), 1.0f),
                    fminf(fmaxf(m2, 0.0f), 1.0f), fminf(fmaxf(m3, 0.0f), 1.0f)};
      uint64_t b0 = __ballot(inb && (m0 > 0.0f));
      uint64_t b1 = __ballot(inb && (m1 > 0.0f));
      uint64_t b2 = __ballot(inb && (m2 > 0.0f));
      uint64_t b3 = __ballot(inb && (m3 > 0.0f));
      if (lane < 4) {                          // inline deinterleave
        int q = lane;
        uint64_t v = spread4((b0 >> (16 * q)) & 0xFFFFull)
                   | (spread4((b1 >> (16 * q)) & 0xFFFFull) << 1)
                   | (spread4((b2 >> (16 * q)) & 0xFFFFull) << 2)
                   | (spread4((b3 >> (16 * q)) & 0xFFFFull) << 3);
        sPos[4 * G + q] = v;
      }
    }
    if (k + 4 < NITER) LDU(up0, k + 4);
    if (k + 2 < NITER) LDPW(k + 2);
  }
  // issue row1's first prefetches now: they drain while wave 0 runs C(0)
  LDU(up1, 0); LDU(up1, 1); LDU(up1, 2); LDU(up1, 3); LDPW(0); LDPW(1);
  __syncthreads();

  // ---- C(0) ---------------------------------------------------------------
  if (tid < 64) graph_live(sPos, sLv, lane);
  __syncthreads();

  // ---- D(0) ---------------------------------------------------------------
  build_keep(sKeep, sLv, tid);
  __syncthreads();

  // ---- FA: store row0 ∥ compute row1 --------------------------------------
  {
    const int sh = 4 * (lane & 15);
    const int kw0 = lane >> 4;
#pragma unroll
    for (int k = 0; k < NITER; ++k) {
      const int G = wv + k * NWV;               // wave-uniform
      if (G < NGRP) {
        int e4 = G * 64 + lane;
        bool inb = e4 < (PTOT / 4);
        // store row0 from mv[k]
        uint32_t kb = (uint32_t)(sKeep[G * 4 + kw0] >> sh) & 0xFu;
        vf4 m = mv[k];
        if (inb) {
          vf4 o;
          o.x = (kb & 1u) ? m.x : 0.0f;
          o.y = (kb & 2u) ? m.y : 0.0f;
          o.z = (kb & 4u) ? m.z : 0.0f;
          o.w = (kb & 8u) ? m.w : 0.0f;
          __builtin_nontemporal_store(o, &op0[e4]);
        }
        // compute row1 into mv[k]
        vf4 u = ub[k % 4], p = pb[k % 2], w = wb[k % 2];
        float m0 = __fadd_rn(__fdiv_rn(__fsub_rn(p.x, u.x), w.x), 0.5f);
        float m1 = __fadd_rn(__fdiv_rn(__fsub_rn(p.y, u.y), w.y), 0.5f);
        float m2 = __fadd_rn(__fdiv_rn(__fsub_rn(p.z, u.z), w.z), 0.5f);
        float m3 = __fadd_rn(__fdiv_rn(__fsub_rn(p.w, u.w), w.w), 0.5f);
        mv[k] = (vf4){fminf(fmaxf(m0, 0.0f), 1.0f), fminf(fmaxf(m1, 0.0f), 1.0f),
                      fminf(fmaxf(m2, 0.0f), 1.0f), fminf(fmaxf(m3, 0.0f), 1.0f)};
        uint64_t b0 = __ballot(inb && (m0 > 0.0f));
        uint64_t b1 = __ballot(inb && (m1 > 0.0f));
        uint64_t b2 = __ballot(inb && (m2 > 0.0f));
        uint64_t b3 = __ballot(inb && (m3 > 0.0f));
        if (lane < 4) {
          int q = lane;
          uint64_t v = spread4((b0 >> (16 * q)) & 0xFFFFull)
                     | (spread4((b1 >> (16 * q)) & 0xFFFFull) << 1)
                     | (spread4((b2 >> (16 * q)) & 0xFFFFull) << 2)
                     | (spread4((b3 >> (16 * q)) & 0xFFFFull) << 3);
          sPos[4 * G + q] = v;
        }
      }
      if (k + 4 < NITER) LDU(up1, k + 4);
      if (k + 2 < NITER) LDPW(k + 2);
    }
  }
#undef LDU
#undef LDPW
  __syncthreads();

  // ---- C(1) on wave 0 ∥ sKeep re-zero on waves 1-7 ------------------------
  if (tid < 64) {
    graph_live(sPos, sLv, lane);
  } else {
    for (int w = tid - 64; w < NCHP; w += TPB - 64) sKeep[w] = 0ull;
  }
  __syncthreads();

  // ---- D(1) ---------------------------------------------------------------
  build_keep(sKeep, sLv, tid);
  __syncthreads();

  // ---- F(1): store row1 ---------------------------------------------------
  {
    const int sh = 4 * (lane & 15);
    const int kw0 = lane >> 4;
#pragma unroll
    for (int k = 0; k < NITER; ++k) {
      const int G = wv + k * NWV;
      if (G >= NGRP) continue;                   // wave-uniform
      int e4 = G * 64 + lane;
      bool inb = e4 < (PTOT / 4);
      uint32_t kb = (uint32_t)(sKeep[G * 4 + kw0] >> sh) & 0xFu;
      vf4 m = mv[k];
      if (inb) {
        vf4 o;
        o.x = (kb & 1u) ? m.x : 0.0f;
        o.y = (kb & 2u) ? m.y : 0.0f;
        o.z = (kb & 4u) ? m.z : 0.0f;
        o.w = (kb & 8u) ? m.w : 0.0f;
        __builtin_nontemporal_store(o, &op1[e4]);
      }
    }
  }
}

extern "C" void kernel_launch(void* const* d_in, const int* in_sizes, int n_in,
                              void* d_out, int out_size, void* d_ws, size_t ws_size,
                              hipStream_t stream) {
  const float* sp   = (const float*)d_in[0];
  const float* unif = (const float*)d_in[1];
  float* out = (float*)d_out;
  char* ws = (char*)d_ws;
  float* pr = (float*)ws;                                  // 132096 B
  float* wd = (float*)(ws + 132096);                       // 132096 B
  int bz = in_sizes[1] / PTOT;   // 1024

  init_tables<<<dim3(TPAD / 256), dim3(256), 0, stream>>>(sp, pr, wd);
  fused_kernel<<<dim3(bz / 2), dim3(TPB), 0, stream>>>(
      unif, (const vf4*)pr, (const vf4*)wd, out);
}

// Round 14
// 258.600 us; speedup vs baseline: 1.2545x; 1.2545x over previous
//
#include <hip/hip_runtime.h>
#include <stdint.h>

#define NL   12
#define PTOT 32936
#define LMB  32778
#define NCH  515           // ceil(PTOT/64) words of positivity bits
#define NCHP 520           // padded LDS words
#define NGRP 129           // ceil(NCH/4) 256-elem groups (64 float4 / group)
#define BMW  (NGRP * 4)    // 516 contiguous-bit words
#define TPAD (NGRP * 256)  // 33024 padded table elems
#define NSEG 445           // 12 layers * 37 segments + 1 LM segment
#define TPB  512           // threads per block (8 waves)
#define NWV  (TPB / 64)
#define NITER ((NGRP + NWV - 1) / NWV)   // 17 groups per wave (statically unrolled)

typedef float vf4 __attribute__((ext_vector_type(4)));

__device__ __constant__ int c_base[NL] = {0,86,653,1701,3230,5240,7731,10703,14156,18090,22505,27401};

__device__ __forceinline__ uint64_t ext(const uint64_t* P, uint32_t off) {
  uint32_t w = off >> 6, s = off & 63;
  uint64_t lo = P[w], hi = P[w + 1];
  return s ? ((lo >> s) | (hi << (64 - s))) : lo;
}

__device__ __forceinline__ uint64_t rbit(uint64_t r0, uint64_t r1, uint64_t r2, uint32_t idx) {
  uint64_t w = idx < 64 ? r0 : (idx < 128 ? r1 : r2);
  return (w >> (idx & 63)) & 1ull;
}

// register-resident ext over the 158-bit live vector (bits >=192 implied 0)
__device__ __forceinline__ uint64_t rext(uint64_t a0, uint64_t a1, uint64_t a2, uint32_t off) {
  uint32_t w = off >> 6, s = off & 63;
  uint64_t lo = (w == 0) ? a0 : ((w == 1) ? a1 : ((w == 2) ? a2 : 0ull));
  uint64_t hi = (w == 0) ? a1 : ((w == 1) ? a2 : 0ull);
  return s ? ((lo >> s) | (hi << (64 - s))) : lo;
}

__device__ __forceinline__ void orAt(uint64_t& r0, uint64_t& r1, uint64_t& r2,
                                     uint64_t val, uint32_t pos) {
  uint32_t w = pos >> 6, s = pos & 63;
  uint64_t lo = val << s;
  uint64_t hi = s ? (val >> (64 - s)) : 0ull;
  if (w == 0) { r0 |= lo; r1 |= hi; }
  else if (w == 1) { r1 |= lo; r2 |= hi; }
  else { r2 |= lo; }
}

__device__ __forceinline__ void maskLen(uint32_t len, uint64_t& m0, uint64_t& m1, uint64_t& m2) {
  m0 = (len >= 64) ? ~0ull : ((1ull << len) - 1ull);
  m1 = (len <= 64) ? 0ull : ((len >= 128) ? ~0ull : ((1ull << (len - 64)) - 1ull));
  m2 = (len <= 128) ? 0ull : ((1ull << (len - 128)) - 1ull);
}

__device__ __forceinline__ uint32_t ext12(uint64_t O0, uint64_t O1, uint64_t O2, uint32_t pos) {
  uint32_t w = pos >> 6, s = pos & 63;
  uint64_t lo = (w == 0) ? O0 : ((w == 1) ? O1 : O2);
  uint64_t hi = (w == 0) ? O1 : ((w == 1) ? O2 : 0ull);
  uint64_t v = s ? ((lo >> s) | (hi << (64 - s))) : lo;
  return (uint32_t)v & 0xFFFu;
}

// spread 16 bits to every 4th bit of a 64-bit word
__device__ __forceinline__ uint64_t spread4(uint64_t x) {
  x = (x | (x << 24)) & 0x000000FF000000FFull;
  x = (x | (x << 12)) & 0x000F000F000F000Full;
  x = (x | (x << 6))  & 0x0303030303030303ull;
  x = (x | (x << 3))  & 0x1111111111111111ull;
  return x;
}

// Per-param tables: pr = prob', hw = 0.5*window (exact), rw = 1/window (CR).
__global__ void init_tables(const float* __restrict__ sp, float* __restrict__ pr,
                            float* __restrict__ hw, float* __restrict__ rw) {
  int p = blockIdx.x * blockDim.x + threadIdx.x;
  if (p >= TPAD) return;
  if (p < PTOT) {
    float x = sp[p];
    float s = 1.0f / (1.0f + expf(-x));                 // sigmoid, fp32
    float w = __fmul_rn(s, __fsub_rn(1.0f, s));         // window = p*(1-p)
    float pv = __fadd_rn(__fmul_rn(w, s), __fmul_rn(__fsub_rn(1.0f, w), s));
    pr[p] = pv;
    hw[p] = __fmul_rn(0.5f, w);                         // exact (x 2^-1)
    rw[p] = __fdiv_rn(1.0f, w);                         // correctly rounded
  } else {
    pr[p] = 0.0f; hw[p] = 0.5f; rw[p] = 1.0f;
  }
}

// ---- Fused kernel: one 512-thread block per row (round-9 structure) ---------
// HBM traffic = read unif once + write out once (compulsory minimum).
// Division-free hot path, BIT-EXACT positivity:
//   d = p - u;  s = d + 0.5w.  Near cancellation s is EXACT (Sterbenz), and
//   the reference's fl-chain positivity (fl(fl(d/w)+0.5) > 0  <=>
//   fl(d/w) > -0.5) can only disagree with (s > 0) when |d/w + 0.5| <= 2^-25,
//   i.e. |s| <= w*2^-25.  We guard a 4x wider band |s| <= w*2^-23 and redo the
//   exact __fdiv_rn chain there (probability ~2^-25/sample: ~never executes).
//   Values use fmaf(d, 1/w, 0.5) — <=2e-7 off the reference, far inside the
//   absmax tolerance, and CANNOT flip graph bits (those come from s / the
//   exact fallback).
__global__ __launch_bounds__(TPB, 4) void fused_kernel(const float* __restrict__ unif,
                                                       const vf4* __restrict__ pr4,
                                                       const vf4* __restrict__ hw4,
                                                       const vf4* __restrict__ rw4,
                                                       float* __restrict__ out) {
  __shared__ uint64_t sPos[NCHP];    // contiguous positivity bits
  __shared__ uint64_t sKeep[NCHP];   // phase A: ballot staging; D/F: keep bits
  __shared__ uint64_t sLv[4];        // live = R & O

  const int tid  = threadIdx.x;
  const int lane = tid & 63;
  const int wv   = tid >> 6;
  const int row  = blockIdx.x;
  const vf4* up4 = (const vf4*)(unif + (size_t)row * PTOT);
  vf4*       op4 = (vf4*)(out + (size_t)row * PTOT);

  vf4 mv[NITER];                     // per-thread registered CLIPPED values

  // ---- Phase A: stream u -> val (registers) + exact ballot (2-deep) -------
  {
    vf4 u = {0.f,0.f,0.f,0.f}, p = {0.f,0.f,0.f,0.f};
    vf4 h = {0.5f,0.5f,0.5f,0.5f}, r = {1.f,1.f,1.f,1.f};
    {
      int e4 = wv * 64 + lane;       // k=0: always in-bounds (G<=7)
      u = up4[e4]; p = pr4[e4]; h = hw4[e4]; r = rw4[e4];
    }
#pragma unroll
    for (int k = 0; k < NITER; ++k) {
      const int G = wv + k * NWV;
      const bool act = G < NGRP;                 // wave-uniform
      // issue next iteration's loads
      vf4 un = {0.f,0.f,0.f,0.f}, pn = {0.f,0.f,0.f,0.f};
      vf4 hn = {0.5f,0.5f,0.5f,0.5f}, rn = {1.f,1.f,1.f,1.f};
      if (k + 1 < NITER) {
        const int Gn = G + NWV;
        if (Gn < NGRP) {
          int e4n = Gn * 64 + lane;
          bool inbn = e4n < (PTOT / 4);
          un = inbn ? up4[e4n] : (vf4){0.f,0.f,0.f,0.f};
          pn = pr4[e4n]; hn = hw4[e4n]; rn = rw4[e4n];
        }
      }
      if (act) {
        int e4 = G * 64 + lane;
        bool inb = e4 < (PTOT / 4);
        float d0 = __fsub_rn(p.x, u.x), d1 = __fsub_rn(p.y, u.y);
        float d2 = __fsub_rn(p.z, u.z), d3 = __fsub_rn(p.w, u.w);
        float s0 = __fadd_rn(d0, h.x), s1 = __fadd_rn(d1, h.y);
        float s2 = __fadd_rn(d2, h.z), s3 = __fadd_rn(d3, h.w);
        bool p0 = s0 > 0.0f, p1 = s1 > 0.0f, p2 = s2 > 0.0f, p3 = s3 > 0.0f;
        float v0 = fminf(fmaxf(__fmaf_rn(d0, r.x, 0.5f), 0.0f), 1.0f);
        float v1 = fminf(fmaxf(__fmaf_rn(d1, r.y, 0.5f), 0.0f), 1.0f);
        float v2 = fminf(fmaxf(__fmaf_rn(d2, r.z, 0.5f), 0.0f), 1.0f);
        float v3 = fminf(fmaxf(__fmaf_rn(d3, r.w, 0.5f), 0.0f), 1.0f);
        // boundary band: |s| <= w*2^-23 = h*2^-22
        const float BF = 2.3841858e-7f;            // 2^-22
        bool nb = (fabsf(s0) <= h.x * BF) || (fabsf(s1) <= h.y * BF) ||
                  (fabsf(s2) <= h.z * BF) || (fabsf(s3) <= h.w * BF);
        if (__builtin_expect((bool)__any((int)nb), 0)) {
          if (nb) {                                // rare: exact fl-chain
            float m0 = __fadd_rn(__fdiv_rn(d0, __fadd_rn(h.x, h.x)), 0.5f);
            float m1 = __fadd_rn(__fdiv_rn(d1, __fadd_rn(h.y, h.y)), 0.5f);
            float m2 = __fadd_rn(__fdiv_rn(d2, __fadd_rn(h.z, h.z)), 0.5f);
            float m3 = __fadd_rn(__fdiv_rn(d3, __fadd_rn(h.w, h.w)), 0.5f);
            p0 = m0 > 0.0f; p1 = m1 > 0.0f; p2 = m2 > 0.0f; p3 = m3 > 0.0f;
            v0 = fminf(fmaxf(m0, 0.0f), 1.0f);
            v1 = fminf(fmaxf(m1, 0.0f), 1.0f);
            v2 = fminf(fmaxf(m2, 0.0f), 1.0f);
            v3 = fminf(fmaxf(m3, 0.0f), 1.0f);
          }
        }
        mv[k] = (vf4){v0, v1, v2, v3};
        uint64_t b0 = __ballot(inb && p0);
        uint64_t b1 = __ballot(inb && p1);
        uint64_t b2 = __ballot(inb && p2);
        uint64_t b3 = __ballot(inb && p3);
        if (lane < 4) {
          uint64_t v = (lane == 0) ? b0 : (lane == 1) ? b1 : (lane == 2) ? b2 : b3;
          sKeep[G * 4 + lane] = v;
        }
      }
      u = un; p = pn; h = hn; r = rn;
    }
  }
  __syncthreads();

  // ---- Phase B: deinterleave ballots -> contiguous-bit words; zero sKeep --
  for (int G = tid; G < NGRP; G += TPB) {
    uint64_t b0 = sKeep[4 * G], b1 = sKeep[4 * G + 1];
    uint64_t b2 = sKeep[4 * G + 2], b3 = sKeep[4 * G + 3];
#pragma unroll
    for (int q = 0; q < 4; ++q) {
      uint64_t v = spread4((b0 >> (16 * q)) & 0xFFFFull)
                 | (spread4((b1 >> (16 * q)) & 0xFFFFull) << 1)
                 | (spread4((b2 >> (16 * q)) & 0xFFFFull) << 2)
                 | (spread4((b3 >> (16 * q)) & 0xFFFFull) << 3);
      sPos[4 * G + q] = v;
      sKeep[4 * G + q] = 0ull;
    }
  }
  for (int w = BMW + tid; w < NCHP; w += TPB) { sPos[w] = 0ull; sKeep[w] = 0ull; }
  __syncthreads();

  // ---- Phase C: forward R then backward O on wave 0 -----------------------
  if (tid < 64) {
    uint64_t R0 = 3ull, R1 = 0ull, R2 = 0ull;
    const int g = lane;
#pragma unroll
    for (int L = 0; L < NL; ++L) {
      const int Vq = 2 + 13 * L;
      const int b  = c_base[L];
      bool pred = false;
      if (g < 36) {
        uint32_t off = (uint32_t)(b + g * Vq);
        uint64_t e0 = ext(sPos, off), e1 = ext(sPos, off + 64), e2 = ext(sPos, off + 128);
        pred = ((e0 & R0) | (e1 & R1) | (e2 & R2)) != 0ull;
      }
      uint64_t bal = __ballot(pred);
      uint64_t ar  = bal & (bal >> 12) & (bal >> 24) & 0xFFFull;
      orAt(R0, R1, R2, ar, (uint32_t)Vq);
      const int Vm = Vq + 12;
      uint32_t offm = (uint32_t)(b + 36 * Vq);
      uint64_t e0 = ext(sPos, offm), e1 = ext(sPos, offm + 64), e2 = ext(sPos, offm + 128);
      uint64_t mr = (((e0 & R0) | (e1 & R1) | (e2 & R2)) != 0ull) ? 1ull : 0ull;
      orAt(R0, R1, R2, mr, (uint32_t)Vm);
    }

    // backward liveness with on-the-fly R-masking (O ⊆ R)
    uint64_t O0 = ext(sPos, LMB)       & R0;
    uint64_t O1 = ext(sPos, LMB + 64)  & R1;
    uint64_t O2 = ext(sPos, LMB + 128) & ((1ull << 30) - 1ull) & R2;
    const int hg = g % 12;
#pragma unroll
    for (int L = NL - 1; L >= 0; --L) {
      const int Vq = 2 + 13 * L, Vm = Vq + 12;
      const int b  = c_base[L];
      if (rbit(O0, O1, O2, (uint32_t)Vm)) {
        uint64_t m0, m1, m2; maskLen((uint32_t)Vm, m0, m1, m2);
        uint32_t offm = (uint32_t)(b + 36 * Vq);
        O0 |= ext(sPos, offm)       & R0 & m0;
        O1 |= ext(sPos, offm + 64)  & R1 & m1;
        O2 |= ext(sPos, offm + 128) & R2 & m2;
      }
      uint32_t h12 = ext12(O0, O1, O2, (uint32_t)Vq);
      uint64_t q0, q1, q2; maskLen((uint32_t)Vq, q0, q1, q2);
      uint64_t c0 = 0ull, c1 = 0ull, c2 = 0ull;
      if (g < 36 && ((h12 >> hg) & 1u)) {
        uint32_t off = (uint32_t)(b + g * Vq);
        c0 = ext(sPos, off)       & R0 & q0;
        c1 = ext(sPos, off + 64)  & R1 & q1;
        c2 = ext(sPos, off + 128) & R2 & q2;
      }
#pragma unroll
      for (int d = 32; d; d >>= 1) {
        c0 |= __shfl_xor((unsigned long long)c0, d);
        c1 |= __shfl_xor((unsigned long long)c1, d);
        c2 |= __shfl_xor((unsigned long long)c2, d);
      }
      O0 |= c0; O1 |= c1; O2 |= c2;
    }
    if (lane == 0) {
      sLv[0] = R0 & O0; sLv[1] = R1 & O1; sLv[2] = R2 & O2; sLv[3] = 0ull;
    }
  }
  __syncthreads();

  // ---- Phase D: build keep bitvector via shifted live windows -------------
  {
    const uint64_t l0 = sLv[0], l1 = sLv[1], l2 = sLv[2];
    for (int s = tid; s < NSEG; s += TPB) {
      uint32_t p0, len;
      bool olive;
      if (s == NSEG - 1) {               // LM tail: keep[i] = live[i]
        p0 = LMB; len = 158; olive = true;
      } else {
        int L = s / 37, j = s - L * 37;
        int Vq = 2 + 13 * L, b = c_base[L];
        if (j < 36) { p0 = (uint32_t)(b + j * Vq); len = (uint32_t)Vq;
                      olive = rbit(l0, l1, l2, (uint32_t)(Vq + (j % 12))) != 0ull; }
        else        { p0 = (uint32_t)(b + 36 * Vq); len = (uint32_t)(Vq + 12);
                      olive = rbit(l0, l1, l2, (uint32_t)(Vq + 12)) != 0ull; }
      }
      if (!olive) continue;
      uint32_t w0 = p0 >> 6, s0 = p0 & 63;
      uint64_t first = l0;
      if (len < 64) first &= (1ull << len) - 1ull;
      atomicOr((unsigned long long*)&sKeep[w0], (unsigned long long)(first << s0));
      uint32_t done = 64 - s0;
      uint32_t w = w0 + 1;
      while (done < len) {
        uint64_t v = rext(l0, l1, l2, done);
        uint32_t rem = len - done;
        if (rem < 64) v &= (1ull << rem) - 1ull;
        atomicOr((unsigned long long*)&sKeep[w], (unsigned long long)v);
        done += 64; ++w;
      }
    }
  }
  __syncthreads();

  // ---- Phase F: apply keep to registered values + streaming store ---------
  // Param index of lane's element c: P = G*256 + 4*lane + c
  //   -> keep word G*4 + (lane>>4), bits 4*(lane&15)+c (nibble per lane).
  {
    const int sh = 4 * (lane & 15);
    const int kw0 = lane >> 4;
#pragma unroll
    for (int k = 0; k < NITER; ++k) {
      const int G = wv + k * NWV;
      if (G >= NGRP) continue;                   // wave-uniform
      int e4 = G * 64 + lane;
      bool inb = e4 < (PTOT / 4);
      uint32_t kb = (uint32_t)(sKeep[G * 4 + kw0] >> sh) & 0xFu;
      vf4 m = mv[k];
      if (inb) {
        vf4 o;
        o.x = (kb & 1u) ? m.x : 0.0f;
        o.y = (kb & 2u) ? m.y : 0.0f;
        o.z = (kb & 4u) ? m.z : 0.0f;
        o.w = (kb & 8u) ? m.w : 0.0f;
        __builtin_nontemporal_store(o, &op4[e4]);
      }
    }
  }
}

extern "C" void kernel_launch(void* const* d_in, const int* in_sizes, int n_in,
                              void* d_out, int out_size, void* d_ws, size_t ws_size,
                              hipStream_t stream) {
  const float* sp   = (const float*)d_in[0];
  const float* unif = (const float*)d_in[1];
  float* out = (float*)d_out;
  char* ws = (char*)d_ws;
  float* pr = (float*)ws;                                  // 132096 B
  float* hw = (float*)(ws + 132096);                       // 132096 B
  float* rw = (float*)(ws + 264192);                       // 132096 B
  int bz = in_sizes[1] / PTOT;   // 1024

  init_tables<<<dim3(TPAD / 256), dim3(256), 0, stream>>>(sp, pr, hw, rw);
  fused_kernel<<<dim3(bz), dim3(TPB), 0, stream>>>(
      unif, (const vf4*)pr, (const vf4*)hw, (const vf4*)rw, out);
}